// Round 3
// baseline (1334.639 us; speedup 1.0000x reference)
//
#include <hip/hip_runtime.h>
#include <stdint.h>

// ---------------- problem constants ----------------
#define PB 16            // batches
#define PN 8192          // points per batch
#define PG 512           // FPS samples (centers) per batch
#define PK 32            // knn group size
#define PTOK 384
#define PM (PB*PG)       // 8192 groups total
#define PMK (PM*PK)      // 262144 MLP rows
static constexpr float BN_EPS_C = 1e-5f;

typedef short bh8  __attribute__((ext_vector_type(8)));
typedef float f32x4 __attribute__((ext_vector_type(4)));
typedef float f32x2 __attribute__((ext_vector_type(2)));

__device__ __forceinline__ short f2bf(float f){
  unsigned u = __float_as_uint(f);
  unsigned r = u + 0x7fffu + ((u>>16)&1u);   // RNE
  return (short)(r>>16);
}
__device__ __forceinline__ float bf2f(short s){
  return __uint_as_float(((unsigned)(unsigned short)s)<<16);
}
__device__ __forceinline__ void gload16(const void* g, void* l){
  __builtin_amdgcn_global_load_lds((const __attribute__((address_space(1))) unsigned int*)g,
                                   (__attribute__((address_space(3))) unsigned int*)l,
                                   16, 0, 0);
}

// packed fp32 math (CDNA full-rate 2-wide, IEEE-exact per half, order preserved)
__device__ __forceinline__ f32x2 pk_add(f32x2 a, f32x2 b){
  f32x2 d; asm("v_pk_add_f32 %0, %1, %2" : "=v"(d) : "v"(a), "v"(b)); return d;
}
__device__ __forceinline__ f32x2 pk_mul(f32x2 a, f32x2 b){
  f32x2 d; asm("v_pk_mul_f32 %0, %1, %2" : "=v"(d) : "v"(a), "v"(b)); return d;
}

// full-wave max via DPP; valid result in lane 63. Requires x >= 0.
__device__ __forceinline__ float wave_max_f32_dpp(float x){
  int v = __float_as_int(x);
#define FMAX_STEP(ctrl) { int o_ = __builtin_amdgcn_update_dpp(v, v, ctrl, 0xf, 0xf, false); \
    v = __float_as_int(fmaxf(__int_as_float(v), __int_as_float(o_))); }
  FMAX_STEP(0x111)  // row_shr:1
  FMAX_STEP(0x112)  // row_shr:2
  FMAX_STEP(0x114)  // row_shr:4
  FMAX_STEP(0x118)  // row_shr:8
  FMAX_STEP(0x142)  // row_bcast:15
  FMAX_STEP(0x143)  // row_bcast:31
#undef FMAX_STEP
  return __int_as_float(v);
}
__device__ __forceinline__ unsigned wave_max_u32_dpp(unsigned x){
  int v = (int)x;   // values fit in [0, 8191]
#define UMAX_STEP(ctrl) { int o_ = __builtin_amdgcn_update_dpp(v, v, ctrl, 0xf, 0xf, false); \
    v = (o_ > v) ? o_ : v; }
  UMAX_STEP(0x111) UMAX_STEP(0x112) UMAX_STEP(0x114) UMAX_STEP(0x118)
  UMAX_STEP(0x142) UMAX_STEP(0x143)
#undef UMAX_STEP
  return (unsigned)v;
}

// 16-lane-row u64 max via DPP (rows of 16; after steps 1/2/4/8 lanes 15/31/47/63
// hold the row max; all rows carry identical data here, so lane 63 = global max).
__device__ __forceinline__ unsigned long long row16_max_u64_dpp(unsigned long long x){
  unsigned lo = (unsigned)x, hi = (unsigned)(x >> 32);
#define U64_STEP(ctrl) { \
    unsigned olo = (unsigned)__builtin_amdgcn_update_dpp((int)lo, (int)lo, ctrl, 0xf, 0xf, false); \
    unsigned ohi = (unsigned)__builtin_amdgcn_update_dpp((int)hi, (int)hi, ctrl, 0xf, 0xf, false); \
    unsigned long long o = ((unsigned long long)ohi << 32) | olo; \
    unsigned long long c = ((unsigned long long)hi  << 32) | lo;  \
    if (o > c){ lo = olo; hi = ohi; } }
  U64_STEP(0x111)  // row_shr:1
  U64_STEP(0x112)  // row_shr:2
  U64_STEP(0x114)  // row_shr:4
  U64_STEP(0x118)  // row_shr:8
#undef U64_STEP
  return ((unsigned long long)hi << 32) | lo;
}

// ---------------- 1. FPS: spatially-pruned, EXACT ------------------------------
// R2 change: the 16 wave-serialized same-address ds_max_rtn_u64 atomics are
// replaced by per-wave slot writes (conflict-free) + a lane-parallel 16-slot
// DPP u64-max after the (single) barrier. Semantics identical: global winner =
// lexicographic max over the 16 current wave keys (md_bits<<32 | lowc).
// 3-slot rotation keeps the one-barrier structure race-free.
__global__ __launch_bounds__(1024, 4) void fps_kernel(const float* __restrict__ points,
                                                      float* __restrict__ centers){
#pragma clang fp contract(off)
  const int b = blockIdx.x;
  const int t = threadIdx.x;
  const float* P = points + (size_t)b*PN*3;
  __shared__ float4 Lc[PN];                        // 128 KB coords by ORIG index
  __shared__ unsigned short sidx[PN];              // 16 KB sorted->orig
  __shared__ int shist[512];                       // 9-bit Morton bins
  __shared__ int spart[64];
  __shared__ unsigned long long swk[3][16];        // per-wave keys, 3-slot rotation
  if (t < 512) shist[t] = 0;
  __syncthreads();
  int mycell[8];
#pragma unroll
  for (int i=0;i<8;i++){
    int j = i*1024 + t;
    float x=P[j*3+0], y=P[j*3+1], z=P[j*3+2];
    Lc[j] = make_float4(x,y,z,0.f);
    int qx=(int)fminf(fmaxf((x+4.f)*1.0f,0.f),7.f);
    int qy=(int)fminf(fmaxf((y+4.f)*1.0f,0.f),7.f);
    int qz=(int)fminf(fmaxf((z+4.f)*1.0f,0.f),7.f);
    int mc = (qx&1)|((qx&2)<<2)|((qx&4)<<4)
           | ((qy&1)<<1)|((qy&2)<<3)|((qy&4)<<5)
           | ((qz&1)<<2)|((qz&2)<<4)|((qz&4)<<6);
    mycell[i]=mc;
    atomicAdd(&shist[mc],1);
  }
  __syncthreads();
  if (t < 64){
    int acc=0;
#pragma unroll
    for (int k=0;k<8;k++){ int h=shist[t*8+k]; shist[t*8+k]=acc; acc+=h; }
    spart[t]=acc;
  }
  __syncthreads();
  if (t==0){ int acc=0; for (int k=0;k<64;k++){ int h=spart[k]; spart[k]=acc; acc+=h; } }
  __syncthreads();
  if (t < 64){
    int off=spart[t];
#pragma unroll
    for (int k=0;k<8;k++) shist[t*8+k] += off;
  }
  __syncthreads();
#pragma unroll
  for (int i=0;i<8;i++){
    int j = i*1024 + t;
    int r = atomicAdd(&shist[mycell[i]],1);
    sidx[r] = (unsigned short)j;
  }
  __syncthreads();
  f32x2 pxp[4], pyp[4], pzp[4];
  float md[8]; int lowc[8];
  float tlx=1e30f,tly=1e30f,tlz=1e30f,thx=-1e30f,thy=-1e30f,thz=-1e30f;
#pragma unroll
  for (int i=0;i<8;i++){
    int oj = sidx[t*8+i];
    float4 p4 = Lc[oj];
    float x=p4.x, y=p4.y, z=p4.z;
    pxp[i>>1][i&1]=x; pyp[i>>1][i&1]=y; pzp[i>>1][i&1]=z;
    md[i]=1e10f; lowc[i]=PN-1-oj;
    tlx=fminf(tlx,x); thx=fmaxf(thx,x);
    tly=fminf(tly,y); thy=fmaxf(thy,y);
    tlz=fminf(tlz,z); thz=fmaxf(thz,z);
  }
#pragma unroll
  for (int off=32; off; off>>=1){
    tlx=fminf(tlx,__shfl_xor(tlx,off)); thx=fmaxf(thx,__shfl_xor(thx,off));
    tly=fminf(tly,__shfl_xor(tly,off)); thy=fmaxf(thy,__shfl_xor(thy,off));
    tlz=fminf(tlz,__shfl_xor(tlz,off)); thz=fmaxf(thz,__shfl_xor(thz,off));
  }
  unsigned long long wkey = ((unsigned long long)0x7F800000u)<<32;
  float cx=P[0], cy=P[1], cz=P[2];
  if (t==0){ float* c = centers + (size_t)b*PG*3; c[0]=cx; c[1]=cy; c[2]=cz; }
  const int lane = t & 63;
  const int wvid = t >> 6;
  __syncthreads();
  for (int g=1; g<PG; g++){
    const int sl = g%3;
    float ddx=fmaxf(fmaxf(tlx-cx, cx-thx),0.f);
    float ddy=fmaxf(fmaxf(tly-cy, cy-thy),0.f);
    float ddz=fmaxf(fmaxf(tlz-cz, cz-thz),0.f);
    float dmin2=((ddx*ddx+ddy*ddy)+ddz*ddz)*0.999999f;
    if (!(dmin2 >= __uint_as_float((unsigned)(wkey>>32)))){
      f32x2 ncx2; ncx2[0]=-cx; ncx2[1]=-cx;
      f32x2 ncy2; ncy2[0]=-cy; ncy2[1]=-cy;
      f32x2 ncz2; ncz2[0]=-cz; ncz2[1]=-cz;
      float mx = 0.f;                              // md >= 0 always
#pragma unroll
      for (int j=0;j<4;j++){
        f32x2 dx = pk_add(pxp[j], ncx2);           // x - cx (exact)
        f32x2 dy = pk_add(pyp[j], ncy2);
        f32x2 dz = pk_add(pzp[j], ncz2);
        f32x2 sx = pk_mul(dx, dx);
        f32x2 sy = pk_mul(dy, dy);
        f32x2 sz = pk_mul(dz, dz);
        f32x2 s1 = pk_add(sx, sy);                 // dx*dx + dy*dy
        f32x2 d2 = pk_add(s1, sz);                 // (dx*dx+dy*dy) + dz*dz
        md[2*j]   = fminf(md[2*j],   d2[0]);
        md[2*j+1] = fminf(md[2*j+1], d2[1]);
        mx = fmaxf(mx, fmaxf(md[2*j], md[2*j+1]));
      }
      // wave max of md (DPP), then exact tie-break: max lowc among md==wmax
      mx = wave_max_f32_dpp(mx);
      float wmax = __int_as_float(__builtin_amdgcn_readlane(__float_as_int(mx), 63));
      unsigned c = 0u;
#pragma unroll
      for (int i=0;i<8;i++)
        if (md[i]==wmax && (unsigned)lowc[i] > c) c = (unsigned)lowc[i];
      c = wave_max_u32_dpp(c);
      unsigned cw = (unsigned)__builtin_amdgcn_readlane((int)c, 63);
      wkey = ((unsigned long long)__float_as_uint(wmax)<<32) | cw;
    }
    if (lane==0) swk[sl][wvid] = wkey;             // parallel slot write (no atomic)
    __syncthreads();                               // the only barrier per iteration
    unsigned long long v = swk[sl][lane & 15];     // conflict-free / broadcast read
    unsigned long long w = row16_max_u64_dpp(v);   // 4-step DPP max over 16 slots
    unsigned rlo = (unsigned)__builtin_amdgcn_readlane((int)(unsigned)w, 63);
    int j = PN-1 - (int)rlo;
    float4 c4 = Lc[j];
    cx = c4.x; cy = c4.y; cz = c4.z;
    if (t==0){ float* cc = centers + ((size_t)b*PG + g)*3; cc[0]=cx; cc[1]=cy; cc[2]=cz; }
  }
}

// ---------------- 2. KNN: exact top-32, incremental lmin + owner rescan --------
__global__ __launch_bounds__(256) void knn_kernel(const float* __restrict__ points,
                                                  const float* __restrict__ centers,
                                                  float* __restrict__ groups){
#pragma clang fp contract(off)
  const int m = blockIdx.x;
  const int b = m >> 9;       // m / PG
  const int t = threadIdx.x;
  const float* P = points + (size_t)b*PN*3;
  const float* c = centers + (size_t)m*3;
  const float cx=c[0], cy=c[1], cz=c[2];
  const float cn = (cx*cx + cy*cy) + cz*cz;
  unsigned long long key[PK];
#pragma unroll
  for (int i=0;i<PK;i++){
    int j = i*256 + t;
    float x=P[j*3+0], y=P[j*3+1], z=P[j*3+2];
    float pn = (x*x + y*y) + z*z;
    float e  = (cx*x + cy*y) + cz*z;
    float d2 = (cn + pn) - 2.0f*e;                 // reference formula
    unsigned u = __float_as_uint(d2);
    u ^= (u & 0x80000000u) ? 0xFFFFFFFFu : 0x80000000u;   // total order
    key[i] = ((unsigned long long)u << 32) | (unsigned)j;
  }
  unsigned long long lmin = key[0];
#pragma unroll
  for (int i=1;i<PK;i++) if (key[i] < lmin) lmin = key[i];
  __shared__ unsigned long long swk[2][4];
  __shared__ int s_idx[PK];
  const int lane = t & 63, wid = t >> 6;
  for (int it=0; it<PK; it++){
    unsigned long long v = lmin;
#pragma unroll
    for (int off=32; off; off>>=1){
      unsigned long long o = __shfl_down(v, off);
      if (o < v) v = o;
    }
    if (lane==0) swk[it&1][wid] = v;
    __syncthreads();                               // the only barrier per round
    unsigned long long w = swk[it&1][0];
#pragma unroll
    for (int q=1;q<4;q++) if (swk[it&1][q] < w) w = swk[it&1][q];
    int wj = (int)(w & 0xFFFFFFFFull);
    if (t==0) s_idx[it] = wj;
    if ((wj & 255) == t){                          // owner-only knockout + rescan
#pragma unroll
      for (int i=0;i<PK;i++) if (key[i] == w) key[i] = ~0ull;
      lmin = key[0];
#pragma unroll
      for (int i=1;i<PK;i++) if (key[i] < lmin) lmin = key[i];
    }
  }
  __syncthreads();
  if (t < PK*3){
    int k = t/3, cc = t - k*3;
    int j = s_idx[k];
    groups[((size_t)m*PK + k)*3 + cc] = P[j*3+cc] - c[cc];
  }
}

// ---------------- 3. layer1: 3->128 linear + BN1 + ReLU, fp32 VALU ----------------
__global__ __launch_bounds__(256) void layer1_kernel(const float* __restrict__ groups,
                                                     const float* __restrict__ w1,
                                                     const float* __restrict__ sc1,
                                                     const float* __restrict__ sh1,
                                                     short* __restrict__ f1){
  int idx = blockIdx.x*256 + threadIdx.x;   // [mk, d], d fastest (slice-local)
  int d  = idx & 127;
  int mk = idx >> 7;
  const float* x = groups + (size_t)mk*3;
  float a = x[0]*w1[d*3+0] + x[1]*w1[d*3+1] + x[2]*w1[d*3+2];
  float y = a*sc1[d] + sh1[d];
  f1[idx] = f2bf(fmaxf(y, 0.f));
}

// ---------------- 4. bf16 MFMA GEMM: C[M,N] = A[M,K] @ B[N,K]^T ----------------
// 1D grid, XCD-aware decomposition: all bn sharing a bm get ids congruent mod 8
// => same XCD (round-robin assignment) => A-tile fetched once into that XCD's
// L2 and re-read from L2 for the other bn (HBM A-traffic / NB). Bijection:
// id = a*8*NB + b*8 + c -> bm = 8a+c, bn = b (requires MB%8==0; runtime
// fallback to plain decompose otherwise — only the tiny H-GEMM can hit it).
// EPI 0: store fp32 raw (H).      EPI 1: +bias[col], store bf16.
// EPI 2: relu(bn2(acc+H[row/32])), store bf16.
// EPI 3: +bias, store bf16 AND fused k-maxpool -> pool_bf (128 rows = 4 groups).
// EPI 4: +bias, fused k-maxpool only -> pool_f (f4 never materialized).
template<int EPI>
__global__ __launch_bounds__(256) void gemm_bt(const short* __restrict__ A,
                                               const short* __restrict__ Bw,
                                               float* __restrict__ Cf,
                                               short* __restrict__ Cb,
                                               int Nn, int Kd,
                                               const float* __restrict__ aux0,
                                               const float* __restrict__ scale,
                                               const float* __restrict__ shift,
                                               short* __restrict__ pool_bf,
                                               float* __restrict__ pool_f){
  __shared__ __align__(16) short smem[(EPI>=3) ? 16384 : 8192];   // 32 KB / 16 KB
  short* As = smem;
  short* Bs = smem + 4096;
  const int NB = Nn >> 7;
  const int MB = (int)gridDim.x / NB;
  int bm, bn;
  {
    int id = blockIdx.x;
    if ((MB & 7) == 0){
      int c = id & 7, q = id >> 3;
      bn = q % NB;
      bm = (q / NB)*8 + c;
    } else {
      bn = id % NB;
      bm = id / NB;
    }
  }
  const int t = threadIdx.x;
  const int lane = t & 63, wid = t >> 6;
  const int wr = wid >> 1, wc = wid & 1;          // 2x2 waves, each 64x64
  f32x4 acc[4][4] = {};
  const int srow = lane >> 2;                      // staging: row within 16-row chunk
  const int scol = (lane & 3) * 8;                 // staging: 8-elem column offset
  const int frow = lane & 15;                      // fragment row/col
  const int fk   = (lane >> 4) * 8;                // fragment k offset
  for (int k0 = 0; k0 < Kd; k0 += 32){
    const size_t abase = ((size_t)bm*128) * Kd + k0 + scol;
    const size_t bbase = ((size_t)bn*128) * Kd + k0 + scol;
    for (int q=0;q<2;q++){
      int chunk = wid*2 + q;                       // 8 chunks x 16 rows = 128 rows
      gload16(A  + abase + (size_t)(chunk*16 + srow)*Kd, &As[chunk*512]);
      gload16(Bw + bbase + (size_t)(chunk*16 + srow)*Kd, &Bs[chunk*512]);
    }
    __syncthreads();                               // vmcnt(0) drained by compiler
    bh8 af[4], bf[4];
    for (int i=0;i<4;i++) af[i] = *(const bh8*)&As[(wr*64 + i*16 + frow)*32 + fk];
    for (int j=0;j<4;j++) bf[j] = *(const bh8*)&Bs[(wc*64 + j*16 + frow)*32 + fk];
    for (int i=0;i<4;i++)
      for (int j=0;j<4;j++)
        acc[i][j] = __builtin_amdgcn_mfma_f32_16x16x32_bf16(af[i], bf[j], acc[i][j], 0, 0, 0);
    __syncthreads();                               // protect LDS for next stage
  }
  const int rb = (lane >> 4) * 4;                  // C/D: col=lane&15, row=(lane>>4)*4+reg
  const int cb = lane & 15;
  for (int i=0;i<4;i++){
    for (int j=0;j<4;j++){
      int lcol = wc*64 + j*16 + cb;
      int col  = bn*128 + lcol;
      for (int r=0;r<4;r++){
        int lrow = wr*64 + i*16 + rb + r;
        size_t row = (size_t)bm*128 + lrow;
        float v = acc[i][j][r];
        if (EPI == 0){
          Cf[row*Nn + col] = v;
        } else if (EPI == 1){
          Cb[row*Nn + col] = f2bf(v + aux0[col]);
        } else if (EPI == 2){
          v += aux0[(row >> 5)*Nn + col];          // + g@w3a^T per group (slice-local)
          v = v*scale[col] + shift[col];           // BN2
          Cb[row*Nn + col] = f2bf(fmaxf(v, 0.f));  // ReLU
        } else {
          short bv = f2bf(v + aux0[col]);
          if (EPI == 3) Cb[row*Nn + col] = bv;     // f2 still needed downstream
          smem[lrow*128 + lcol] = bv;              // stage tile for fused pool
        }
      }
    }
  }
  if (EPI >= 3){
    __syncthreads();                               // tile complete in LDS
    int c = t & 127, gsel = t >> 7;                // 256 thr -> 2 (group,col) each
#pragma unroll
    for (int gg=0; gg<2; gg++){
      int g = gsel*2 + gg;                         // 0..3 within tile
      float mx = -3.4e38f;
#pragma unroll
      for (int k=0;k<PK;k++) mx = fmaxf(mx, bf2f(smem[(g*32 + k)*128 + c]));
      size_t grow = (size_t)bm*4 + g;
      int gcol = bn*128 + c;
      if (EPI == 3) pool_bf[grow*256  + gcol] = f2bf(mx);
      else          pool_f [grow*PTOK + gcol] = mx;
    }
  }
}

// ---------------- 0. weight conversion + BN folding ----------------
__global__ __launch_bounds__(256) void prep_kernel(const float* __restrict__ w2,
    const float* __restrict__ w3, const float* __restrict__ w4,
    const float* __restrict__ g1, const float* __restrict__ be1,
    const float* __restrict__ mu1, const float* __restrict__ va1,
    const float* __restrict__ g2, const float* __restrict__ be2,
    const float* __restrict__ mu2, const float* __restrict__ va2,
    short* __restrict__ w2b, short* __restrict__ w3ab, short* __restrict__ w3bb,
    short* __restrict__ w4b, float* __restrict__ sc1, float* __restrict__ sh1,
    float* __restrict__ sc2, float* __restrict__ sh2){
  int i = blockIdx.x*256 + threadIdx.x;
  if (i < 256*128) w2b[i] = f2bf(w2[i]);
  if (i < 512*512){
    int f = i >> 9, e = i & 511;
    short v = f2bf(w3[i]);
    if (e < 256) w3ab[f*256 + e] = v; else w3bb[f*256 + (e-256)] = v;
  }
  if (i < 384*512) w4b[i] = f2bf(w4[i]);
  if (i < 128){ float s = g1[i]*rsqrtf(va1[i] + BN_EPS_C); sc1[i]=s; sh1[i]=be1[i]-mu1[i]*s; }
  if (i < 512){ float s = g2[i]*rsqrtf(va2[i] + BN_EPS_C); sc2[i]=s; sh2[i]=be2[i]-mu2[i]*s; }
}

// ---------------- launcher ----------------
extern "C" void kernel_launch(void* const* d_in, const int* in_sizes, int n_in,
                              void* d_out, int out_size, void* d_ws, size_t ws_size,
                              hipStream_t stream){
  const float* points = (const float*)d_in[0];
  const float* w1  = (const float*)d_in[1];
  const float* g1  = (const float*)d_in[2];
  const float* be1 = (const float*)d_in[3];
  const float* mu1 = (const float*)d_in[4];
  const float* va1 = (const float*)d_in[5];
  const float* w2  = (const float*)d_in[6];
  const float* b2  = (const float*)d_in[7];
  const float* w3  = (const float*)d_in[8];
  const float* g2  = (const float*)d_in[9];
  const float* be2 = (const float*)d_in[10];
  const float* mu2 = (const float*)d_in[11];
  const float* va2 = (const float*)d_in[12];
  const float* w4  = (const float*)d_in[13];
  const float* b4  = (const float*)d_in[14];
  float* tokens  = (float*)d_out;                       // [PM, 384]
  float* centers = (float*)d_out + (size_t)PM*PTOK;     // [PM, 3]

  // ---- fixed workspace region (~25.1 MB) ----
  char* ws = (char*)d_ws;
  float* grp  = (float*)(ws + 0);              // 262144x3 fp32  = 3 MB
  short* gbuf = (short*)(ws + 3145728ull);     // 8192x256 bf16  = 4 MB
  float* Hbuf = (float*)(ws + 7340032ull);     // 8192x512 fp32  = 16 MB
  short* w2b  = (short*)(ws + 24117248ull);    // 256x128 bf16
  short* w3ab = (short*)(ws + 24182784ull);    // 512x256 bf16
  short* w3bb = (short*)(ws + 24444928ull);    // 512x256 bf16
  short* w4b  = (short*)(ws + 24707072ull);    // 384x512 bf16
  float* sc1  = (float*)(ws + 25100288ull);
  float* sh1  = (float*)(ws + 25100800ull);
  float* sc2  = (float*)(ws + 25101312ull);
  float* sh2  = (float*)(ws + 25103360ull);
  const size_t sliceBase = 25105408ull;

  // ---- adaptive row-slicing: peak slice use = 1792 bytes/row ----
  size_t avail = (ws_size > sliceBase) ? (ws_size - sliceBase) : 0;
  long long smax = (long long)(avail / 1792u);
  int S = (int)((smax / 4096) * 4096);
  if (S > PMK) S = PMK;
  if (S < 4096) S = 4096;   // below ~32 MB ws nothing fits; best effort
  char* sl = ws + sliceBase;

  prep_kernel<<<1024, 256, 0, stream>>>(w2, w3, w4, g1, be1, mu1, va1, g2, be2, mu2, va2,
                                        w2b, w3ab, w3bb, w4b, sc1, sh1, sc2, sh2);
  fps_kernel<<<PB, 1024, 0, stream>>>(points, centers);
  knn_kernel<<<PM, 256, 0, stream>>>(points, centers, grp);

  for (int r0 = 0; r0 < PMK; r0 += S){
    int rows = (PMK - r0 < S) ? (PMK - r0) : S;    // multiple of 4096
    int g0 = r0 >> 5, ng = rows >> 5;              // groups in slice
    short* f1 = (short*)(sl + 0);                  // rows x 128 bf16
    short* f2 = (short*)(sl + (size_t)S*256);      // rows x 256 bf16
    short* f3 = (short*)(sl + (size_t)S*768);      // rows x 512 bf16

    layer1_kernel<<<(rows*128)/256, 256, 0, stream>>>(grp + (size_t)r0*3, w1, sc1, sh1, f1);
    // f2 = f1 @ w2^T + b2, fused g = maxpool_k(f2)   [NB=2]
    gemm_bt<3><<<(rows/128)*2, 256, 0, stream>>>(f1, w2b, nullptr, f2, 256, 128,
                                                 b2, nullptr, nullptr,
                                                 gbuf + (size_t)g0*256, nullptr);
    // H = g @ w3[:, :256]^T   [NB=4]
    gemm_bt<0><<<(ng/128)*4, 256, 0, stream>>>(gbuf + (size_t)g0*256, w3ab,
                                               Hbuf + (size_t)g0*512, nullptr, 512, 256,
                                               nullptr, nullptr, nullptr, nullptr, nullptr);
    // f3 = relu(bn2(f2 @ w3[:, 256:]^T + H[group]))   [NB=4]
    gemm_bt<2><<<(rows/128)*4, 256, 0, stream>>>(f2, w3bb, nullptr, f3, 512, 256,
                                                 Hbuf + (size_t)g0*512, sc2, sh2,
                                                 nullptr, nullptr);
    // tokens = maxpool_k(f3 @ w4^T + b4), f4 never materialized   [NB=3]
    gemm_bt<4><<<(rows/128)*3, 256, 0, stream>>>(f3, w4b, nullptr, nullptr, 384, 512,
                                                 b4, nullptr, nullptr,
                                                 nullptr, tokens + (size_t)g0*384);
  }
}

// Round 4
// 1222.509 us; speedup vs baseline: 1.0917x; 1.0917x over previous
//
#include <hip/hip_runtime.h>
#include <stdint.h>

// ---------------- problem constants ----------------
#define PB 16            // batches
#define PN 8192          // points per batch
#define PG 512           // FPS samples (centers) per batch
#define PK 32            // knn group size
#define PTOK 384
#define PM (PB*PG)       // 8192 groups total
#define PMK (PM*PK)      // 262144 MLP rows
static constexpr float BN_EPS_C = 1e-5f;

typedef short bh8  __attribute__((ext_vector_type(8)));
typedef float f32x4 __attribute__((ext_vector_type(4)));

__device__ __forceinline__ short f2bf(float f){
  unsigned u = __float_as_uint(f);
  unsigned r = u + 0x7fffu + ((u>>16)&1u);   // RNE
  return (short)(r>>16);
}
__device__ __forceinline__ float bf2f(short s){
  return __uint_as_float(((unsigned)(unsigned short)s)<<16);
}
__device__ __forceinline__ void gload16(const void* g, void* l){
  __builtin_amdgcn_global_load_lds((const __attribute__((address_space(1))) unsigned int*)g,
                                   (__attribute__((address_space(3))) unsigned int*)l,
                                   16, 0, 0);
}

// ---------------- 1. FPS: spatially-pruned, EXACT (round-0 original, best=507us) ---
__global__ __launch_bounds__(1024, 4) void fps_kernel(const float* __restrict__ points,
                                                      float* __restrict__ centers){
#pragma clang fp contract(off)
  const int b = blockIdx.x;
  const int t = threadIdx.x;
  const float* P = points + (size_t)b*PN*3;
  __shared__ float4 Lc[PN];                        // 128 KB coords by ORIG index
  __shared__ unsigned short sidx[PN];              // 16 KB sorted->orig
  __shared__ int shist[512];                       // 9-bit Morton bins
  __shared__ int spart[64];
  __shared__ unsigned long long swa[3];
  if (t < 512) shist[t] = 0;
  if (t < 3)   swa[t] = 0ull;
  __syncthreads();
  int mycell[8];
#pragma unroll
  for (int i=0;i<8;i++){
    int j = i*1024 + t;
    float x=P[j*3+0], y=P[j*3+1], z=P[j*3+2];
    Lc[j] = make_float4(x,y,z,0.f);
    int qx=(int)fminf(fmaxf((x+4.f)*1.0f,0.f),7.f);
    int qy=(int)fminf(fmaxf((y+4.f)*1.0f,0.f),7.f);
    int qz=(int)fminf(fmaxf((z+4.f)*1.0f,0.f),7.f);
    int mc = (qx&1)|((qx&2)<<2)|((qx&4)<<4)
           | ((qy&1)<<1)|((qy&2)<<3)|((qy&4)<<5)
           | ((qz&1)<<2)|((qz&2)<<4)|((qz&4)<<6);
    mycell[i]=mc;
    atomicAdd(&shist[mc],1);
  }
  __syncthreads();
  if (t < 64){
    int acc=0;
#pragma unroll
    for (int k=0;k<8;k++){ int h=shist[t*8+k]; shist[t*8+k]=acc; acc+=h; }
    spart[t]=acc;
  }
  __syncthreads();
  if (t==0){ int acc=0; for (int k=0;k<64;k++){ int h=spart[k]; spart[k]=acc; acc+=h; } }
  __syncthreads();
  if (t < 64){
    int off=spart[t];
#pragma unroll
    for (int k=0;k<8;k++) shist[t*8+k] += off;
  }
  __syncthreads();
#pragma unroll
  for (int i=0;i<8;i++){
    int j = i*1024 + t;
    int r = atomicAdd(&shist[mycell[i]],1);
    sidx[r] = (unsigned short)j;
  }
  __syncthreads();
  float px[8],py[8],pz[8],md[8]; int lowc[8];
  float tlx=1e30f,tly=1e30f,tlz=1e30f,thx=-1e30f,thy=-1e30f,thz=-1e30f;
#pragma unroll
  for (int i=0;i<8;i++){
    int oj = sidx[t*8+i];
    float4 p4 = Lc[oj];
    float x=p4.x, y=p4.y, z=p4.z;
    px[i]=x; py[i]=y; pz[i]=z; md[i]=1e10f; lowc[i]=PN-1-oj;
    tlx=fminf(tlx,x); thx=fmaxf(thx,x);
    tly=fminf(tly,y); thy=fmaxf(thy,y);
    tlz=fminf(tlz,z); thz=fmaxf(thz,z);
  }
#pragma unroll
  for (int off=32; off; off>>=1){
    tlx=fminf(tlx,__shfl_xor(tlx,off)); thx=fmaxf(thx,__shfl_xor(thx,off));
    tly=fminf(tly,__shfl_xor(tly,off)); thy=fmaxf(thy,__shfl_xor(thy,off));
    tlz=fminf(tlz,__shfl_xor(tlz,off)); thz=fmaxf(thz,__shfl_xor(thz,off));
  }
  unsigned long long wkey = ((unsigned long long)0x7F800000u)<<32;
  float cx=P[0], cy=P[1], cz=P[2];
  if (t==0){ float* c = centers + (size_t)b*PG*3; c[0]=cx; c[1]=cy; c[2]=cz; }
  const int lane = t & 63;
  __syncthreads();
  for (int g=1; g<PG; g++){
    const int sl = g%3, ns = (g+1)%3;
    float ddx=fmaxf(fmaxf(tlx-cx, cx-thx),0.f);
    float ddy=fmaxf(fmaxf(tly-cy, cy-thy),0.f);
    float ddz=fmaxf(fmaxf(tlz-cz, cz-thz),0.f);
    float dmin2=((ddx*ddx+ddy*ddy)+ddz*ddz)*0.999999f;
    if (!(dmin2 >= __uint_as_float((unsigned)(wkey>>32)))){
      unsigned long long bk = 0ull;
#pragma unroll
      for (int i=0;i<8;i++){
        float dx=px[i]-cx, dy=py[i]-cy, dz=pz[i]-cz;
        float d2 = (dx*dx + dy*dy) + dz*dz;
        md[i] = fminf(md[i], d2);
        unsigned long long ki = ((unsigned long long)__float_as_uint(md[i])<<32)
                              | (unsigned)lowc[i];
        if (ki > bk) bk = ki;
      }
#pragma unroll
      for (int mask=32; mask; mask>>=1){
        unsigned long long o = __shfl_xor(bk, mask);
        if (o > bk) bk = o;
      }
      wkey = bk;
    }
    if (lane==0) atomicMax(&swa[sl], wkey);
    if (t==0) swa[ns] = 0ull;
    __syncthreads();
    unsigned long long w = swa[sl];
    int j = PN-1 - (int)(w & 0xFFFFFFFFu);
    float4 c4 = Lc[j];
    cx = c4.x; cy = c4.y; cz = c4.z;
    if (t==0){ float* cc = centers + ((size_t)b*PG + g)*3; cc[0]=cx; cc[1]=cy; cc[2]=cz; }
  }
}

// ---------------- 2. KNN: exact top-32, incremental lmin + owner rescan --------
__global__ __launch_bounds__(256) void knn_kernel(const float* __restrict__ points,
                                                  const float* __restrict__ centers,
                                                  float* __restrict__ groups){
#pragma clang fp contract(off)
  const int m = blockIdx.x;
  const int b = m >> 9;       // m / PG
  const int t = threadIdx.x;
  const float* P = points + (size_t)b*PN*3;
  const float* c = centers + (size_t)m*3;
  const float cx=c[0], cy=c[1], cz=c[2];
  const float cn = (cx*cx + cy*cy) + cz*cz;
  unsigned long long key[PK];
#pragma unroll
  for (int i=0;i<PK;i++){
    int j = i*256 + t;
    float x=P[j*3+0], y=P[j*3+1], z=P[j*3+2];
    float pn = (x*x + y*y) + z*z;
    float e  = (cx*x + cy*y) + cz*z;
    float d2 = (cn + pn) - 2.0f*e;                 // reference formula
    unsigned u = __float_as_uint(d2);
    u ^= (u & 0x80000000u) ? 0xFFFFFFFFu : 0x80000000u;   // total order
    key[i] = ((unsigned long long)u << 32) | (unsigned)j;
  }
  unsigned long long lmin = key[0];
#pragma unroll
  for (int i=1;i<PK;i++) if (key[i] < lmin) lmin = key[i];
  __shared__ unsigned long long swk[2][4];
  __shared__ int s_idx[PK];
  const int lane = t & 63, wid = t >> 6;
  for (int it=0; it<PK; it++){
    unsigned long long v = lmin;
#pragma unroll
    for (int off=32; off; off>>=1){
      unsigned long long o = __shfl_down(v, off);
      if (o < v) v = o;
    }
    if (lane==0) swk[it&1][wid] = v;
    __syncthreads();                               // the only barrier per round
    unsigned long long w = swk[it&1][0];
#pragma unroll
    for (int q=1;q<4;q++) if (swk[it&1][q] < w) w = swk[it&1][q];
    int wj = (int)(w & 0xFFFFFFFFull);
    if (t==0) s_idx[it] = wj;
    if ((wj & 255) == t){                          // owner-only knockout + rescan
#pragma unroll
      for (int i=0;i<PK;i++) if (key[i] == w) key[i] = ~0ull;
      lmin = key[0];
#pragma unroll
      for (int i=1;i<PK;i++) if (key[i] < lmin) lmin = key[i];
    }
  }
  __syncthreads();
  if (t < PK*3){
    int k = t/3, cc = t - k*3;
    int j = s_idx[k];
    groups[((size_t)m*PK + k)*3 + cc] = P[j*3+cc] - c[cc];
  }
}

// ---------------- 3. fused MLP: layer1 -> f2 -> pool g -> f3(concat) -> f4 -> pool ----
// One block = 128 rows = 4 complete groups. All intermediates (f1,f2,g,f3) live in
// LDS; f4 partials accumulate in registers across 4 N-chunks of f3. Replaces
// layer1_kernel + gemm_bt<3,0,2,4>, Hbuf/gbuf/f1/f2/f3 HBM traffic, and slicing.
//   f2  = f2bf(f1 @ w2^T + b2)              (f1 = relu(bn1(grp @ w1^T)))
//   g   = f2bf(maxpool_k(f2))               per group
//   f3  = f2bf(relu(bn2([g,f2] @ w3^T)))    K=512 concat (g part k<256 via w3ab)
//   tok = maxpool_k(f3 @ w4^T) + b4         fp32
// LDS chunk layout for A-operands: [k-chunk][row][32] (m97 pattern, proven here).
__global__ __launch_bounds__(512, 2) void mlp_kernel(const float* __restrict__ grp,
                                                     const float* __restrict__ w1,
                                                     const float* __restrict__ sc1,
                                                     const float* __restrict__ sh1,
                                                     const short* __restrict__ w2b,
                                                     const float* __restrict__ b2,
                                                     const short* __restrict__ w3ab,
                                                     const short* __restrict__ w3bb,
                                                     const float* __restrict__ sc2,
                                                     const float* __restrict__ sh2,
                                                     const short* __restrict__ w4b,
                                                     const float* __restrict__ b4,
                                                     float* __restrict__ tokens){
  __shared__ __align__(16) short s_f1f3[16384];    // 32 KB: f1 [4][128][32] then f3-chunk
  __shared__ __align__(16) short s_f2[32768];      // 64 KB: f2 [8][128][32]
  __shared__ __align__(16) short s_g[1024];        //  2 KB: g  [4][256]
  __shared__ __align__(16) short s_bst[24576];     // 48 KB: B staging [2][R][32]
  const int t = threadIdx.x;
  const int lane = t & 63, wid = t >> 6;
  const int mh = wid >> 1, nq = wid & 1;           // 4 M-waves x 2 N-waves
  const int B0 = blockIdx.x * 128;                 // first row of block
  const int G0 = blockIdx.x * 4;                   // first group of block
  const int srow = lane >> 2;                      // staging row within 16-row chunk
  const int scol = (lane & 3) * 8;                 // staging col offset
  const int frow = lane & 15;                      // fragment row
  const int fk   = (lane >> 4) * 8;                // fragment k offset
  const int rb   = (lane >> 4) * 4;                // C/D row base
  const int cb   = lane & 15;                      // C/D col

  // ---- phase A: layer1 into f1 (LDS) ----
  {
    int r = t & 127, dg = t >> 7;                  // thread: row r, d-range dg*32..+31
    float x0 = grp[(size_t)(B0+r)*3 + 0];
    float x1 = grp[(size_t)(B0+r)*3 + 1];
    float x2 = grp[(size_t)(B0+r)*3 + 2];
#pragma unroll
    for (int dd=0; dd<32; dd++){
      int d = dg*32 + dd;
      float a = x0*w1[d*3+0] + x1*w1[d*3+1] + x2*w1[d*3+2];
      float y = a*sc1[d] + sh1[d];
      s_f1f3[dg*4096 + r*32 + dd] = f2bf(fmaxf(y, 0.f));
    }
  }
  __syncthreads();

  // ---- phase B: f2 = f1 @ w2^T + b2 (K=128, N=256) ----
  {
    f32x4 accB[2][8] = {};
    for (int k0=0; k0<128; k0+=64){
      for (int cc=wid; cc<32; cc+=8){              // stage w2 [2][256][32]
        int sub = cc & 1, rc = cc >> 1;
        int r = rc*16 + srow;
        gload16(w2b + (size_t)r*128 + k0 + sub*32 + scol, &s_bst[sub*8192 + rc*512]);
      }
      __syncthreads();
#pragma unroll
      for (int sub=0; sub<2; sub++){
        int kc = (k0 + sub*32) >> 5;
        bh8 af[2], bf[8];
#pragma unroll
        for (int i=0;i<2;i++)
          af[i] = *(const bh8*)&s_f1f3[kc*4096 + (mh*32 + i*16 + frow)*32 + fk];
#pragma unroll
        for (int j=0;j<8;j++)
          bf[j] = *(const bh8*)&s_bst[sub*8192 + (nq*128 + j*16 + frow)*32 + fk];
#pragma unroll
        for (int i=0;i<2;i++)
#pragma unroll
          for (int j=0;j<8;j++)
            accB[i][j] = __builtin_amdgcn_mfma_f32_16x16x32_bf16(af[i], bf[j], accB[i][j], 0,0,0);
      }
      __syncthreads();
    }
    // epilogue: +b2, bf16, write f2 chunks
#pragma unroll
    for (int i=0;i<2;i++)
#pragma unroll
      for (int j=0;j<8;j++){
        int col = nq*128 + j*16 + cb;
#pragma unroll
        for (int r=0;r<4;r++){
          int row = mh*32 + i*16 + rb + r;
          s_f2[(col>>5)*4096 + row*32 + (col&31)] = f2bf(accB[i][j][r] + b2[col]);
        }
      }
  }
  __syncthreads();

  // ---- phase C: g = maxpool_k(f2) per group ----
  {
#pragma unroll
    for (int task=0; task<2; task++){
      int g = (t>>8) + task*2;                     // 0..3
      int col = t & 255;
      int kc = col >> 5, c5 = col & 31;
      float mx = -3.4e38f;
#pragma unroll
      for (int kk=0; kk<PK; kk++)
        mx = fmaxf(mx, bf2f(s_f2[kc*4096 + (g*32 + kk)*32 + c5]));
      s_g[g*256 + col] = f2bf(mx);
    }
  }
  __syncthreads();

  // ---- phases D+E: f3 chunks (concat GEMM) + f4 partial accumulation ----
  f32x4 acc4[2][12] = {};                          // persistent: 128 x 384 over 8 waves
  for (int nc=0; nc<4; nc++){
    // --- D: f3c[128][128] = relu(bn2([g,f2] @ w3[nc*128..][:]^T)) ---
    f32x4 acc3[2][4] = {};
    for (int k0=0; k0<512; k0+=64){
      const short* w3s = (k0 < 256) ? w3ab : w3bb;
      int kk0 = (k0 < 256) ? k0 : (k0 - 256);
      for (int cc=wid; cc<16; cc+=8){              // stage w3 [2][128][32]
        int sub = cc & 1, rc = cc >> 1;
        int r = nc*128 + rc*16 + srow;
        gload16(w3s + (size_t)r*256 + kk0 + sub*32 + scol, &s_bst[sub*4096 + rc*512]);
      }
      __syncthreads();
#pragma unroll
      for (int sub=0; sub<2; sub++){
        int k = k0 + sub*32;                       // concat-k
        bh8 af[2], bf[4];
        if (k < 256){
#pragma unroll
          for (int i=0;i<2;i++)                    // whole wave-tile = one group: broadcast
            af[i] = *(const bh8*)&s_g[mh*256 + k + fk];
        } else {
          int kc = (k - 256) >> 5;
#pragma unroll
          for (int i=0;i<2;i++)
            af[i] = *(const bh8*)&s_f2[kc*4096 + (mh*32 + i*16 + frow)*32 + fk];
        }
#pragma unroll
        for (int j=0;j<4;j++)
          bf[j] = *(const bh8*)&s_bst[sub*4096 + (nq*64 + j*16 + frow)*32 + fk];
#pragma unroll
        for (int i=0;i<2;i++)
#pragma unroll
          for (int j=0;j<4;j++)
            acc3[i][j] = __builtin_amdgcn_mfma_f32_16x16x32_bf16(af[i], bf[j], acc3[i][j], 0,0,0);
      }
      __syncthreads();
    }
    // D epilogue: bn2 + relu + bf16 -> f3 chunk (reuses f1 region)
#pragma unroll
    for (int i=0;i<2;i++)
#pragma unroll
      for (int j=0;j<4;j++){
        int cl = nq*64 + j*16 + cb;                // local f-col 0..127
        int f  = nc*128 + cl;
        float s = sc2[f], h = sh2[f];
#pragma unroll
        for (int r=0;r<4;r++){
          int row = mh*32 + i*16 + rb + r;
          float v = acc3[i][j][r]*s + h;
          s_f1f3[(cl>>5)*4096 + row*32 + (cl&31)] = f2bf(fmaxf(v, 0.f));
        }
      }
    __syncthreads();
    // --- E: acc4 += f3c @ w4[:, nc*128..]^T (K-chunk of 128) ---
    for (int kk0=0; kk0<128; kk0+=64){
      for (int cc=wid; cc<48; cc+=8){              // stage w4 [2][384][32]
        int sub = cc & 1, rc = cc >> 1;
        int r = rc*16 + srow;
        gload16(w4b + (size_t)r*512 + nc*128 + kk0 + sub*32 + scol, &s_bst[sub*12288 + rc*512]);
      }
      __syncthreads();
#pragma unroll
      for (int sub=0; sub<2; sub++){
        int kc = (kk0 + sub*32) >> 5;
        bh8 af[2], bf[12];
#pragma unroll
        for (int i=0;i<2;i++)
          af[i] = *(const bh8*)&s_f1f3[kc*4096 + (mh*32 + i*16 + frow)*32 + fk];
#pragma unroll
        for (int j=0;j<12;j++)
          bf[j] = *(const bh8*)&s_bst[sub*12288 + (nq*192 + j*16 + frow)*32 + fk];
#pragma unroll
        for (int i=0;i<2;i++)
#pragma unroll
          for (int j=0;j<12;j++)
            acc4[i][j] = __builtin_amdgcn_mfma_f32_16x16x32_bf16(af[i], bf[j], acc4[i][j], 0,0,0);
      }
      __syncthreads();
    }
  }

  // ---- phase F: tokens = maxpool_k(f4) + b4 (wave mh owns group mh) ----
#pragma unroll
  for (int j=0;j<12;j++){
    int col = nq*192 + j*16 + cb;
    float mx = -3.4e38f;
#pragma unroll
    for (int i=0;i<2;i++)
#pragma unroll
      for (int r=0;r<4;r++)
        mx = fmaxf(mx, acc4[i][j][r]);
    mx = fmaxf(mx, __shfl_xor(mx, 16));
    mx = fmaxf(mx, __shfl_xor(mx, 32));
    if (lane < 16)
      tokens[(size_t)(G0 + mh)*PTOK + col] = mx + b4[col];
  }
}

// ---------------- 0. weight conversion + BN folding ----------------
__global__ __launch_bounds__(256) void prep_kernel(const float* __restrict__ w2,
    const float* __restrict__ w3, const float* __restrict__ w4,
    const float* __restrict__ g1, const float* __restrict__ be1,
    const float* __restrict__ mu1, const float* __restrict__ va1,
    const float* __restrict__ g2, const float* __restrict__ be2,
    const float* __restrict__ mu2, const float* __restrict__ va2,
    short* __restrict__ w2b, short* __restrict__ w3ab, short* __restrict__ w3bb,
    short* __restrict__ w4b, float* __restrict__ sc1, float* __restrict__ sh1,
    float* __restrict__ sc2, float* __restrict__ sh2){
  int i = blockIdx.x*256 + threadIdx.x;
  if (i < 256*128) w2b[i] = f2bf(w2[i]);
  if (i < 512*512){
    int f = i >> 9, e = i & 511;
    short v = f2bf(w3[i]);
    if (e < 256) w3ab[f*256 + e] = v; else w3bb[f*256 + (e-256)] = v;
  }
  if (i < 384*512) w4b[i] = f2bf(w4[i]);
  if (i < 128){ float s = g1[i]*rsqrtf(va1[i] + BN_EPS_C); sc1[i]=s; sh1[i]=be1[i]-mu1[i]*s; }
  if (i < 512){ float s = g2[i]*rsqrtf(va2[i] + BN_EPS_C); sc2[i]=s; sh2[i]=be2[i]-mu2[i]*s; }
}

// ---------------- launcher ----------------
extern "C" void kernel_launch(void* const* d_in, const int* in_sizes, int n_in,
                              void* d_out, int out_size, void* d_ws, size_t ws_size,
                              hipStream_t stream){
  const float* points = (const float*)d_in[0];
  const float* w1  = (const float*)d_in[1];
  const float* g1  = (const float*)d_in[2];
  const float* be1 = (const float*)d_in[3];
  const float* mu1 = (const float*)d_in[4];
  const float* va1 = (const float*)d_in[5];
  const float* w2  = (const float*)d_in[6];
  const float* b2  = (const float*)d_in[7];
  const float* w3  = (const float*)d_in[8];
  const float* g2  = (const float*)d_in[9];
  const float* be2 = (const float*)d_in[10];
  const float* mu2 = (const float*)d_in[11];
  const float* va2 = (const float*)d_in[12];
  const float* w4  = (const float*)d_in[13];
  const float* b4  = (const float*)d_in[14];
  float* tokens  = (float*)d_out;                       // [PM, 384]
  float* centers = (float*)d_out + (size_t)PM*PTOK;     // [PM, 3]

  // ---- workspace (~4.2 MB total) ----
  char* ws = (char*)d_ws;
  float* grp  = (float*)(ws + 0);              // 262144x3 fp32 = 3 MB
  short* w2b  = (short*)(ws + 3145728ull);     // 256x128 bf16
  short* w3ab = (short*)(ws + 3211264ull);     // 512x256 bf16
  short* w3bb = (short*)(ws + 3473408ull);     // 512x256 bf16
  short* w4b  = (short*)(ws + 3735552ull);     // 384x512 bf16
  float* sc1  = (float*)(ws + 4128768ull);
  float* sh1  = (float*)(ws + 4129280ull);
  float* sc2  = (float*)(ws + 4129792ull);
  float* sh2  = (float*)(ws + 4131840ull);

  prep_kernel<<<1024, 256, 0, stream>>>(w2, w3, w4, g1, be1, mu1, va1, g2, be2, mu2, va2,
                                        w2b, w3ab, w3bb, w4b, sc1, sh1, sc2, sh2);
  fps_kernel<<<PB, 1024, 0, stream>>>(points, centers);
  knn_kernel<<<PM, 256, 0, stream>>>(points, centers, grp);
  mlp_kernel<<<PMK/128, 512, 0, stream>>>(grp, w1, sc1, sh1, w2b, b2,
                                          w3ab, w3bb, sc2, sh2, w4b, b4, tokens);
}